// Round 1
// baseline (310.344 us; speedup 1.0000x reference)
//
#include <hip/hip_runtime.h>
#include <hip/hip_bf16.h>

typedef __hip_bfloat16 bf16;
typedef __attribute__((ext_vector_type(8))) short v8s;
typedef __attribute__((ext_vector_type(4))) short v4s;
typedef __attribute__((ext_vector_type(4))) float v4f;

#define MFMA16(a,b,c) __builtin_amdgcn_mfma_f32_16x16x32_bf16((a),(b),(c),0,0,0)

// ---- problem constants ----
// B=2 S=2048 HID=1024 H=16 D=64, rows = B*S = 4096, Ycols = 5*1024 = 5120
// Y col regions: [0,1024)=q | [1024,2048)=k | [2048,3072)=v | [3072,4096)=g | [4096,5120)=gate

// ---- workspace layout (bytes) ----
static const size_t OFF_XBF    = 0;                          // 4096*1024 bf16
static const size_t OFF_WCATT  = 8388608;                    // 5*1024*1024 bf16 (BT layout: [n][k])
static const size_t OFF_WOT    = OFF_WCATT + 10485760;       // 1024*1024 bf16
static const size_t OFF_Y      = OFF_WOT + 2097152;          // 4096*5120 bf16
static const size_t OFF_BETA   = OFF_Y + 41943040;           // 4096*16 f32
static const size_t OFF_OINTRA = OFF_BETA + 262144;          // 4096*1024 f32
static const size_t OFF_T      = OFF_OINTRA + 16777216;      // (32bh*32c)*4096 f32
static const size_t OFF_S      = OFF_T + 16777216;           // (32bh*32c)*4096 f32
static const size_t OFF_OPRE   = OFF_S + 16777216;           // 4096*1024 bf16

// ---------------------------------------------------------------- cvt x -> bf16
__global__ __launch_bounds__(256) void cvt_x(const float* __restrict__ x, bf16* __restrict__ xb) {
  int idx = (blockIdx.x * 256 + threadIdx.x) * 4;
  v4f v = *(const v4f*)(x + idx);
  union { bf16 h[4]; v4s s; } u;
  for (int i = 0; i < 4; ++i) u.h[i] = __float2bfloat16(v[i]);
  *(v4s*)(xb + idx) = u.s;
}

// ------------------------------------------- transpose+convert 6 weight matrices
__global__ __launch_bounds__(256) void transpose_pack(
    const float* __restrict__ W0, const float* __restrict__ W1, const float* __restrict__ W2,
    const float* __restrict__ W3, const float* __restrict__ W4, const float* __restrict__ W5,
    bf16* __restrict__ WcatT, bf16* __restrict__ WoT)
{
  int mi = blockIdx.z;
  const float* W = (mi==0)?W0:(mi==1)?W1:(mi==2)?W2:(mi==3)?W3:(mi==4)?W4:W5;
  bf16* out = (mi < 5) ? (WcatT + (size_t)mi * 1048576) : WoT;
  __shared__ float tile[64][65];
  int c0 = blockIdx.x * 64;   // col of W (n)
  int r0 = blockIdx.y * 64;   // row of W (k)
  int l = threadIdx.x & 63, w = threadIdx.x >> 6;
  for (int i = 0; i < 16; ++i)
    tile[w + 4*i][l] = W[(size_t)(r0 + w + 4*i) * 1024 + c0 + l];
  __syncthreads();
  for (int i = 0; i < 16; ++i)
    out[(size_t)(c0 + w + 4*i) * 1024 + r0 + l] = __float2bfloat16(tile[l][w + 4*i]);
}

// ------------------------------------------------------------ beta = sigmoid(x@Wb)
__global__ __launch_bounds__(256) void beta_kernel(const float* __restrict__ x,
                                                   const float* __restrict__ Wb,
                                                   float* __restrict__ beta)
{
  int bs = blockIdx.x;
  __shared__ float xr[1024];
  for (int i = threadIdx.x; i < 1024; i += 256) xr[i] = x[(size_t)bs * 1024 + i];
  __syncthreads();
  int w = threadIdx.x >> 6, l = threadIdx.x & 63;
  for (int h = w; h < 16; h += 4) {
    float s = 0.f;
    for (int j = l; j < 1024; j += 64) s += xr[j] * Wb[(size_t)j * 16 + h];
    s += __shfl_xor(s, 32, 64); s += __shfl_xor(s, 16, 64);
    s += __shfl_xor(s, 8, 64);  s += __shfl_xor(s, 4, 64);
    s += __shfl_xor(s, 2, 64);  s += __shfl_xor(s, 1, 64);
    if (l == 0) beta[(size_t)bs * 16 + h] = 1.f / (1.f + __expf(-s));
  }
}

// ------------------------------------------- bf16 MFMA GEMM: C = A[M][K] @ BT[N][K]^T
// mode 0: fused activation epilogue, bf16 out (Y).  mode 1: raw f32 out.
__global__ __launch_bounds__(256) void gemm_bf16(
    const bf16* __restrict__ A, const bf16* __restrict__ BT,
    void* __restrict__ Cout, int M, int N, int K,
    int mode, const float* __restrict__ dtb, const float* __restrict__ bgp)
{
  __shared__ bf16 As[128][72];
  __shared__ bf16 Bs[128][72];
  const int tid = threadIdx.x;
  const int m0 = blockIdx.y * 128, n0 = blockIdx.x * 128;
  const int w = tid >> 6, l = tid & 63;
  const int wm = (w >> 1) * 64, wn = (w & 1) * 64;
  const int lr = l & 15, lk = (l >> 4) * 8;
  v4f acc[4][4];
  for (int i = 0; i < 4; ++i) for (int j = 0; j < 4; ++j) acc[i][j] = (v4f){0.f,0.f,0.f,0.f};
  for (int kk = 0; kk < K; kk += 64) {
    for (int i = 0; i < 4; ++i) {
      int cid = i * 256 + tid;
      int r = cid >> 3, c8 = (cid & 7) * 8;
      *(v8s*)(&As[r][c8]) = *(const v8s*)(&A[(size_t)(m0 + r) * K + kk + c8]);
      *(v8s*)(&Bs[r][c8]) = *(const v8s*)(&BT[(size_t)(n0 + r) * K + kk + c8]);
    }
    __syncthreads();
    v8s af[2][4], bf[2][4];
    for (int kc = 0; kc < 2; ++kc)
      for (int mt = 0; mt < 4; ++mt)
        af[kc][mt] = *(const v8s*)(&As[wm + mt*16 + lr][kc*32 + lk]);
    for (int kc = 0; kc < 2; ++kc)
      for (int nt = 0; nt < 4; ++nt)
        bf[kc][nt] = *(const v8s*)(&Bs[wn + nt*16 + lr][kc*32 + lk]);
    for (int kc = 0; kc < 2; ++kc)
      for (int mt = 0; mt < 4; ++mt)
        for (int nt = 0; nt < 4; ++nt)
          acc[mt][nt] = MFMA16(af[kc][mt], bf[kc][nt], acc[mt][nt]);
    __syncthreads();
  }
  if (mode == 0) {
    bf16* Yb = (bf16*)Cout;
    for (int mt = 0; mt < 4; ++mt)
      for (int nt = 0; nt < 4; ++nt)
        for (int r = 0; r < 4; ++r) {
          int gm = m0 + wm + mt*16 + (l>>4)*4 + r;
          int gn = n0 + wn + nt*16 + lr;
          float y = acc[mt][nt][r];
          int region = gn >> 10, loc = gn & 1023;
          float v;
          if (region < 3)        { v = y / (1.f + __expf(-y)); }            // silu q,k,v
          else if (region == 3)  { float z = y - dtb[loc]; v = 1.f/(1.f+__expf(-z)); } // g
          else                   { float z = y + bgp[loc]; v = 1.f/(1.f+__expf(-z)); } // gate
          Yb[(size_t)gm * N + gn] = __float2bfloat16(v);
        }
  } else {
    float* Co = (float*)Cout;
    for (int mt = 0; mt < 4; ++mt)
      for (int nt = 0; nt < 4; ++nt)
        for (int r = 0; r < 4; ++r) {
          int gm = m0 + wm + mt*16 + (l>>4)*4 + r;
          int gn = n0 + wn + nt*16 + lr;
          Co[(size_t)gm * N + gn] = acc[mt][nt][r];
        }
  }
}

// ------------------------------------------------- l2norm rows of 64 for q,k regions
__global__ __launch_bounds__(256) void l2norm_qk(bf16* Y) {
  int g = blockIdx.x * 4 + (threadIdx.x >> 6);   // 0..131071
  int l = threadIdx.x & 63;
  int which = g & 1;
  int h = (g >> 1) & 15;
  int row = g >> 5;
  size_t base = (size_t)row * 5120 + (size_t)which * 1024 + h * 64;
  float v = __bfloat162float(Y[base + l]);
  float s = v * v;
  s += __shfl_xor(s, 32, 64); s += __shfl_xor(s, 16, 64);
  s += __shfl_xor(s, 8, 64);  s += __shfl_xor(s, 4, 64);
  s += __shfl_xor(s, 2, 64);  s += __shfl_xor(s, 1, 64);
  float n = fmaxf(sqrtf(s), 1e-12f);
  Y[base + l] = __float2bfloat16(v / n);
}

// -------------------------------------------------------- passA: intra-chunk + T_c
// block = (chunk c, bh). Computes Ointra[64][64] and T_c[64][64] with MFMA.
__global__ __launch_bounds__(256) void passA(
    const bf16* __restrict__ Y, const float* __restrict__ beta,
    const float* __restrict__ A_log, float* __restrict__ Ointra, float* __restrict__ T)
{
  int c = blockIdx.x, bh = blockIdx.y;
  int b = bh >> 4, h = bh & 15;
  int row0 = b * 2048 + c * 64;
  __shared__ bf16 Qs[64][72], Ks[64][72], Kt[64][72], Vt[64][72], Ps[64][72];
  __shared__ float betas[64], pw[64];
  int tid = threadIdx.x, w = tid >> 6, l = tid & 63;
  float aexp = __expf(A_log[h]);
  if (tid < 64) {
    pw[tid] = __expf(-aexp * (float)tid);           // A^tid (underflows to 0, ok)
    betas[tid] = beta[(size_t)(row0 + tid) * 16 + h];
  }
  __syncthreads();
  // stage Q,K row-major; K^T (coef-folded) and V^T transposed
  for (int i = 0; i < 2; ++i) {
    int cid = i * 256 + tid;
    int r = cid >> 3, c8 = (cid & 7) * 8;
    size_t ybase = (size_t)(row0 + r) * 5120 + h * 64 + c8;
    v8s q8 = *(const v8s*)(&Y[ybase]);
    v8s k8 = *(const v8s*)(&Y[ybase + 1024]);
    v8s v8 = *(const v8s*)(&Y[ybase + 2048]);
    *(v8s*)(&Qs[r][c8]) = q8;
    *(v8s*)(&Ks[r][c8]) = k8;
    float coefT = pw[63 - r] * betas[r];
    const bf16* kp = (const bf16*)&k8;
    const bf16* vp = (const bf16*)&v8;
    for (int jj = 0; jj < 8; ++jj) {
      Vt[c8 + jj][r] = vp[jj];
      Kt[c8 + jj][r] = __float2bfloat16(coefT * __bfloat162float(kp[jj]));
    }
  }
  __syncthreads();
  const int lr = l & 15, lk = (l >> 4) * 8;
  // P = Q @ K^T  (wave w owns 16-row strip)
  v4f accP[4];
  for (int nt = 0; nt < 4; ++nt) accP[nt] = (v4f){0.f,0.f,0.f,0.f};
  for (int kc = 0; kc < 2; ++kc) {
    v8s a8 = *(const v8s*)(&Qs[w*16 + lr][kc*32 + lk]);
    for (int nt = 0; nt < 4; ++nt) {
      v8s b8 = *(const v8s*)(&Ks[nt*16 + lr][kc*32 + lk]);
      accP[nt] = MFMA16(a8, b8, accP[nt]);
    }
  }
  // mask + decay + beta, write Pm (bf16)
  for (int nt = 0; nt < 4; ++nt)
    for (int r = 0; r < 4; ++r) {
      int tq = w*16 + (l>>4)*4 + r;
      int j  = nt*16 + lr;
      float v = accP[nt][r];
      float pm = (j < tq) ? v * betas[j] * pw[tq - 1 - j] : 0.f;
      Ps[tq][j] = __float2bfloat16(pm);
    }
  __syncthreads();
  // Ointra = Pm @ V ; T = (coef*K)^T @ V
  v4f accO[4], accT[4];
  for (int nt = 0; nt < 4; ++nt) { accO[nt] = (v4f){0.f,0.f,0.f,0.f}; accT[nt] = (v4f){0.f,0.f,0.f,0.f}; }
  for (int kc = 0; kc < 2; ++kc) {
    v8s ap = *(const v8s*)(&Ps[w*16 + lr][kc*32 + lk]);
    v8s ak = *(const v8s*)(&Kt[w*16 + lr][kc*32 + lk]);
    for (int nt = 0; nt < 4; ++nt) {
      v8s b8 = *(const v8s*)(&Vt[nt*16 + lr][kc*32 + lk]);
      accO[nt] = MFMA16(ap, b8, accO[nt]);
      accT[nt] = MFMA16(ak, b8, accT[nt]);
    }
  }
  for (int nt = 0; nt < 4; ++nt)
    for (int r = 0; r < 4; ++r) {
      int row = w*16 + (l>>4)*4 + r;   // tq for O, d for T
      int col = nt*16 + lr;            // e
      Ointra[(size_t)(row0 + row) * 1024 + h*64 + col] = accO[nt][r];
      T[((size_t)(bh*32 + c)) * 4096 + row*64 + col]   = accT[nt][r];
    }
}

// --------------------------------------------- passB: stitch chunk states (32 blocks)
__global__ __launch_bounds__(256) void passB(const float* __restrict__ T,
                                             float* __restrict__ S,
                                             const float* __restrict__ A_log)
{
  int bh = blockIdx.x; int h = bh & 15;
  float aexp = __expf(A_log[h]);
  float A64 = __expf(-aexp * 64.f);   // = 0 in f32 for these inputs; kept general
  int tid = threadIdx.x;
  float s[16];
  for (int i = 0; i < 16; ++i) s[i] = 0.f;
  for (int c = 0; c < 32; ++c) {
    size_t base = ((size_t)(bh * 32 + c)) * 4096;
    for (int i = 0; i < 16; ++i) S[base + i*256 + tid] = s[i];
    if (c < 31)
      for (int i = 0; i < 16; ++i)
        s[i] = A64 * s[i] + T[base + i*256 + tid];
  }
}

// ------------------------- passC: O = g*(intra + decay*Q@S), RMSNorm, gate -> opre bf16
__global__ __launch_bounds__(256) void passC(
    const bf16* __restrict__ Y, const float* __restrict__ Ointra,
    const float* __restrict__ S, const float* __restrict__ A_log,
    const float* __restrict__ norm_w, bf16* __restrict__ opre)
{
  int c = blockIdx.x, bh = blockIdx.y;
  int b = bh >> 4, h = bh & 15;
  int row0 = b * 2048 + c * 64;
  __shared__ bf16 Qs[64][72], St[64][72];
  int tid = threadIdx.x, w = tid >> 6, l = tid & 63;
  float aexp = __expf(A_log[h]);
  for (int i = 0; i < 2; ++i) {
    int cid = i * 256 + tid;
    int r = cid >> 3, c8 = (cid & 7) * 8;
    *(v8s*)(&Qs[r][c8]) = *(const v8s*)(&Y[(size_t)(row0 + r) * 5120 + h*64 + c8]);
  }
  for (int i = 0; i < 16; ++i) {
    int idx = i * 256 + tid;
    int r = idx >> 6, e = idx & 63;
    St[e][r] = __float2bfloat16(S[((size_t)(bh*32 + c)) * 4096 + idx]);
  }
  __syncthreads();
  const int lr = l & 15, lk = (l >> 4) * 8;
  v4f acc[4];
  for (int nt = 0; nt < 4; ++nt) acc[nt] = (v4f){0.f,0.f,0.f,0.f};
  for (int kc = 0; kc < 2; ++kc) {
    v8s a8 = *(const v8s*)(&Qs[w*16 + lr][kc*32 + lk]);
    for (int nt = 0; nt < 4; ++nt) {
      v8s b8 = *(const v8s*)(&St[nt*16 + lr][kc*32 + lk]);
      acc[nt] = MFMA16(a8, b8, acc[nt]);
    }
  }
  for (int r = 0; r < 4; ++r) {
    int tq = w*16 + (l>>4)*4 + r;
    float sc = __expf(-aexp * (float)tq);   // A^(t-t0)
    size_t orow = (size_t)(row0 + tq);
    float o[4];
    float ss = 0.f;
    for (int nt = 0; nt < 4; ++nt) {
      int e = nt*16 + lr;
      float v = Ointra[orow * 1024 + h*64 + e] + sc * acc[nt][r];
      float g = __bfloat162float(Y[orow * 5120 + 3072 + h*64 + e]);
      v *= g;
      o[nt] = v;
      ss += v * v;
    }
    ss += __shfl_xor(ss, 1, 64);
    ss += __shfl_xor(ss, 2, 64);
    ss += __shfl_xor(ss, 4, 64);
    ss += __shfl_xor(ss, 8, 64);
    float rms = rsqrtf(ss * (1.f/64.f) + 1e-5f);
    for (int nt = 0; nt < 4; ++nt) {
      int e = nt*16 + lr;
      float gate = __bfloat162float(Y[orow * 5120 + 4096 + h*64 + e]);
      float outv = o[nt] * rms * norm_w[e] * gate;
      opre[orow * 1024 + h*64 + e] = __float2bfloat16(outv);
    }
  }
}

// ================================================================ launcher
extern "C" void kernel_launch(void* const* d_in, const int* in_sizes, int n_in,
                              void* d_out, int out_size, void* d_ws, size_t ws_size,
                              hipStream_t stream) {
  const float* x       = (const float*)d_in[0];
  const float* Wq      = (const float*)d_in[1];
  const float* Wk      = (const float*)d_in[2];
  const float* Wv      = (const float*)d_in[3];
  const float* Wf      = (const float*)d_in[4];
  const float* Wb      = (const float*)d_in[5];
  const float* A_log   = (const float*)d_in[6];
  const float* dt_bias = (const float*)d_in[7];
  const float* Wg      = (const float*)d_in[8];
  const float* bg      = (const float*)d_in[9];
  const float* Wo      = (const float*)d_in[10];
  const float* norm_w  = (const float*)d_in[11];

  char* ws = (char*)d_ws;
  bf16*  xb     = (bf16*)(ws + OFF_XBF);
  bf16*  wcatT  = (bf16*)(ws + OFF_WCATT);
  bf16*  woT    = (bf16*)(ws + OFF_WOT);
  bf16*  Y      = (bf16*)(ws + OFF_Y);
  float* beta   = (float*)(ws + OFF_BETA);
  float* Ointra = (float*)(ws + OFF_OINTRA);
  float* Tbuf   = (float*)(ws + OFF_T);
  float* Sbuf   = (float*)(ws + OFF_S);
  bf16*  opre   = (bf16*)(ws + OFF_OPRE);

  cvt_x<<<4096, 256, 0, stream>>>(x, xb);
  transpose_pack<<<dim3(16, 16, 6), 256, 0, stream>>>(Wq, Wk, Wv, Wf, Wg, Wo, wcatT, woT);
  beta_kernel<<<4096, 256, 0, stream>>>(x, Wb, beta);
  gemm_bf16<<<dim3(40, 32), 256, 0, stream>>>(xb, wcatT, (void*)Y, 4096, 5120, 1024,
                                              0, dt_bias, bg);
  l2norm_qk<<<32768, 256, 0, stream>>>(Y);
  passA<<<dim3(32, 32), 256, 0, stream>>>(Y, beta, A_log, Ointra, Tbuf);
  passB<<<32, 256, 0, stream>>>(Tbuf, Sbuf, A_log);
  passC<<<dim3(32, 32), 256, 0, stream>>>(Y, Ointra, Sbuf, A_log, norm_w, opre);
  gemm_bf16<<<dim3(8, 32), 256, 0, stream>>>(opre, woT, d_out, 4096, 1024, 1024,
                                             1, nullptr, nullptr);
}